// Round 1
// baseline (707.876 us; speedup 1.0000x reference)
//
#include <hip/hip_runtime.h>
#include <math.h>

#define BB 8
#define NVV 2048
#define NPP 4096
#define DD 64
#define KK 8

// ---------------- ws layout (float offsets) ----------------
// vm      : [16384]            @ 0
// inv_vf  : [16384]            @ 16384
// inv_pf  : [32768]            @ 32768
// flow    : [16384][4]         @ 65536
// pval    : [16384][8][8]      @ 131072      (1,048,576 floats)
// pidx    : [16384][8][8] int  @ 1179648     (1,048,576 ints)
// total ~8.5 MB

// ============ kernel 1: sigmoid + per-batch min-max normalize ============
__global__ __launch_bounds__(256) void k_vm(const float* __restrict__ logits,
                                            float* __restrict__ vm,
                                            float* __restrict__ out) {
  int b = blockIdx.x, t = threadIdx.x;
  __shared__ float smn[4], smx[4];
  float vals[8];
  float mn = 1e30f, mx = -1e30f;
#pragma unroll
  for (int i = 0; i < 8; i++) {
    float x = logits[b * NVV + t + i * 256];
    float s = 1.0f / (1.0f + expf(-x));
    vals[i] = s;
    mn = fminf(mn, s);
    mx = fmaxf(mx, s);
  }
  for (int o = 32; o; o >>= 1) {
    mn = fminf(mn, __shfl_xor(mn, o, 64));
    mx = fmaxf(mx, __shfl_xor(mx, o, 64));
  }
  int w = t >> 6;
  if ((t & 63) == 0) { smn[w] = mn; smx[w] = mx; }
  __syncthreads();
  mn = fminf(fminf(smn[0], smn[1]), fminf(smn[2], smn[3]));
  mx = fmaxf(fmaxf(smx[0], smx[1]), fmaxf(smx[2], smx[3]));
  float range = mx - mn;
#pragma unroll
  for (int i = 0; i < 8; i++) {
    float v = (vals[i] - mn) / range;
    int g = b * NVV + t + i * 256;
    vm[g] = v;
    out[g * 4 + 3] = v;
  }
}

// ============ kernel 2: per-row inverse norms (one wave per row) ============
__global__ __launch_bounds__(256) void k_norms(const float* __restrict__ vf,
                                               const float* __restrict__ pf,
                                               float* __restrict__ inv_vf,
                                               float* __restrict__ inv_pf) {
  int wave = (blockIdx.x * 256 + threadIdx.x) >> 6;
  int lane = threadIdx.x & 63;
  const float* src;
  float* dst;
  int row;
  if (wave < BB * NVV) { src = vf; dst = inv_vf; row = wave; }
  else { src = pf; dst = inv_pf; row = wave - BB * NVV; }
  float x = src[row * DD + lane];
  float s = x * x;
  for (int o = 32; o; o >>= 1) s += __shfl_xor(s, o, 64);
  if (lane == 0) dst[row] = 1.0f / fmaxf(sqrtf(s), 1e-12f);
}

// ============ kernel 3: partial top-8 cosine KNN ============
// One vertex per lane; keys iterated wave-uniformly (scalar loads).
// sim(v,k) = dot(raw_q_v, raw_key_k) * inv_key_norm[k]  (query norm cancels in ranking)
__global__ __launch_bounds__(256) void k_knn(const float* __restrict__ q,
                                             const float* __restrict__ keys,
                                             const float* __restrict__ inv_key,
                                             const float* __restrict__ mask,
                                             float* __restrict__ pval,
                                             int* __restrict__ pidx,
                                             int nq, int nk, int chunk, int nchunks) {
  int bid = blockIdx.x;
  int ck = bid % nchunks;
  int vb = bid / nchunks;
  int qpb = nq / 256;             // query-blocks per batch
  int batch = vb / qpb;
  int qrow = batch * nq + (vb % qpb) * 256 + threadIdx.x;

  float4 qv[16];
  const float4* qp = (const float4*)(q + (long)qrow * DD);
#pragma unroll
  for (int c = 0; c < 16; c++) qv[c] = qp[c];

  float tv[8];
  int ti[8];
#pragma unroll
  for (int k = 0; k < 8; k++) { tv[k] = -1e30f; ti[k] = 0; }
  float thr = -1e30f;

  const float* kbase = keys + (long)batch * nk * DD;
  const float* ibase = inv_key + (long)batch * nk;
  const float* mbase = mask ? (mask + (long)batch * nk) : nullptr;
  int p0 = ck * chunk, p1 = p0 + chunk;
  for (int p = p0; p < p1; p++) {
    int pu = __builtin_amdgcn_readfirstlane(p);   // force wave-uniform key index
    if (mbase && mbase[pu] < 0.5f) continue;      // uniform scalar branch
    const float4* kp = (const float4*)(kbase + (long)pu * DD);
    float4 acc = {0.f, 0.f, 0.f, 0.f};
#pragma unroll
    for (int c = 0; c < 16; c++) {
      float4 kv = kp[c];
      acc.x = fmaf(kv.x, qv[c].x, acc.x);
      acc.y = fmaf(kv.y, qv[c].y, acc.y);
      acc.z = fmaf(kv.z, qv[c].z, acc.z);
      acc.w = fmaf(kv.w, qv[c].w, acc.w);
    }
    float sim = ((acc.x + acc.y) + (acc.z + acc.w)) * ibase[pu];
    if (sim > thr) {
      // replace current-min slot
      float mn = tv[0];
      int sl = 0;
#pragma unroll
      for (int k = 1; k < 8; k++) {
        bool c = tv[k] < mn;
        mn = c ? tv[k] : mn;
        sl = c ? k : sl;
      }
#pragma unroll
      for (int k = 0; k < 8; k++)
        if (k == sl) { tv[k] = sim; ti[k] = pu; }
      mn = tv[0];
#pragma unroll
      for (int k = 1; k < 8; k++) mn = fminf(mn, tv[k]);
      thr = mn;
    }
  }
  float* pv = pval + ((long)qrow * nchunks + ck) * 8;
  int* pi = pidx + ((long)qrow * nchunks + ck) * 8;
#pragma unroll
  for (int k = 0; k < 8; k++) { pv[k] = tv[k]; pi[k] = ti[k]; }
}

__device__ __forceinline__ float dot64(const float4* __restrict__ a,
                                       const float4* __restrict__ b) {
  float4 acc = {0.f, 0.f, 0.f, 0.f};
#pragma unroll
  for (int c = 0; c < 16; c++) {
    float4 x = a[c], y = b[c];
    acc.x = fmaf(x.x, y.x, acc.x);
    acc.y = fmaf(x.y, y.y, acc.y);
    acc.z = fmaf(x.z, y.z, acc.z);
    acc.w = fmaf(x.w, y.w, acc.w);
  }
  return (acc.x + acc.y) + (acc.z + acc.w);
}

// ============ kernel 4: merge KNN1 partials + flow_init ============
// vm cancels in the flow_init ratio -> omitted.
__global__ __launch_bounds__(64) void k_merge_flow(const float* __restrict__ pval,
                                                   const int* __restrict__ pidx,
                                                   const float* __restrict__ vf,
                                                   const float* __restrict__ pf,
                                                   const float* __restrict__ pts,
                                                   const float* __restrict__ vtx,
                                                   float* __restrict__ flow_ws,
                                                   float* __restrict__ out,
                                                   int nchunks) {
  int g = blockIdx.x * 64 + threadIdx.x;  // 0..16383
  int batch = g >> 11;                    // /NVV
  float tv[8];
  int ti[8];
#pragma unroll
  for (int k = 0; k < 8; k++) { tv[k] = -3.0e38f; ti[k] = 0; }
  float thr = -3.0e38f;
  const float* pv = pval + (long)g * nchunks * 8;
  const int* pi = pidx + (long)g * nchunks * 8;
  for (int j = 0; j < nchunks * 8; j++) {
    float v = pv[j];
    if (v > thr) {
      int id = pi[j];
      float mn = tv[0];
      int sl = 0;
#pragma unroll
      for (int k = 1; k < 8; k++) {
        bool c = tv[k] < mn;
        mn = c ? tv[k] : mn;
        sl = c ? k : sl;
      }
#pragma unroll
      for (int k = 0; k < 8; k++)
        if (k == sl) { tv[k] = v; ti[k] = id; }
      mn = tv[0];
#pragma unroll
      for (int k = 1; k < 8; k++) mn = fminf(mn, tv[k]);
      thr = mn;
    }
  }
  // flow_init = sum(euclid * fsim) / sum(fsim), fsim = dot(raw pf_nbr, raw vf)
  float4 qv[16];
  const float4* qp = (const float4*)(vf + (long)g * DD);
#pragma unroll
  for (int c = 0; c < 16; c++) qv[c] = qp[c];
  float ax = 0.f, ay = 0.f, az = 0.f, den = 0.f;
  float vx = vtx[g * 3 + 0], vy = vtx[g * 3 + 1], vz = vtx[g * 3 + 2];
#pragma unroll
  for (int k = 0; k < 8; k++) {
    int prow = batch * NPP + ti[k];
    float w = dot64(qv, (const float4*)(pf + (long)prow * DD));
    float ex = pts[prow * 3 + 0] - vx;
    float ey = pts[prow * 3 + 1] - vy;
    float ez = pts[prow * 3 + 2] - vz;
    ax = fmaf(ex, w, ax);
    ay = fmaf(ey, w, ay);
    az = fmaf(ez, w, az);
    den += w;
  }
  float fx = ax / den, fy = ay / den, fz = az / den;
  flow_ws[g * 4 + 0] = fx;
  flow_ws[g * 4 + 1] = fy;
  flow_ws[g * 4 + 2] = fz;
  out[g * 4 + 0] = fx;
  out[g * 4 + 1] = fy;
  out[g * 4 + 2] = fz;
}

// ============ kernel 5: merge KNN2 partials + interpolate invisible ============
__global__ __launch_bounds__(64) void k_merge_final(const float* __restrict__ pval,
                                                    const int* __restrict__ pidx,
                                                    const float* __restrict__ vf,
                                                    const float* __restrict__ vm,
                                                    const float* __restrict__ flow_ws,
                                                    float* __restrict__ out,
                                                    int nchunks) {
  int g = blockIdx.x * 64 + threadIdx.x;
  if (vm[g] >= 0.5f) return;  // visible: out already holds flow_init
  int batch = g >> 11;
  float tv[8];
  int ti[8];
#pragma unroll
  for (int k = 0; k < 8; k++) { tv[k] = -3.0e38f; ti[k] = 0; }
  float thr = -3.0e38f;
  const float* pv = pval + (long)g * nchunks * 8;
  const int* pi = pidx + (long)g * nchunks * 8;
  for (int j = 0; j < nchunks * 8; j++) {
    float v = pv[j];
    if (v > thr) {
      int id = pi[j];
      float mn = tv[0];
      int sl = 0;
#pragma unroll
      for (int k = 1; k < 8; k++) {
        bool c = tv[k] < mn;
        mn = c ? tv[k] : mn;
        sl = c ? k : sl;
      }
#pragma unroll
      for (int k = 0; k < 8; k++)
        if (k == sl) { tv[k] = v; ti[k] = id; }
      mn = tv[0];
#pragma unroll
      for (int k = 1; k < 8; k++) mn = fminf(mn, tv[k]);
      thr = mn;
    }
  }
  float4 qv[16];
  const float4* qp = (const float4*)(vf + (long)g * DD);
#pragma unroll
  for (int c = 0; c < 16; c++) qv[c] = qp[c];
  float ax = 0.f, ay = 0.f, az = 0.f, den = 0.f;
#pragma unroll
  for (int k = 0; k < 8; k++) {
    int krow = batch * NVV + ti[k];
    float w = dot64(qv, (const float4*)(vf + (long)krow * DD));
    ax = fmaf(flow_ws[krow * 4 + 0], w, ax);
    ay = fmaf(flow_ws[krow * 4 + 1], w, ay);
    az = fmaf(flow_ws[krow * 4 + 2], w, az);
    den += w;
  }
  out[g * 4 + 0] = ax / den;
  out[g * 4 + 1] = ay / den;
  out[g * 4 + 2] = az / den;
}

extern "C" void kernel_launch(void* const* d_in, const int* in_sizes, int n_in,
                              void* d_out, int out_size, void* d_ws, size_t ws_size,
                              hipStream_t stream) {
  const float* vtx = (const float*)d_in[0];
  const float* pts = (const float*)d_in[1];
  const float* vf = (const float*)d_in[2];
  const float* pf = (const float*)d_in[3];
  const float* lg = (const float*)d_in[4];
  float* out = (float*)d_out;
  float* ws = (float*)d_ws;

  float* vm = ws;                    // 16384
  float* inv_vf = ws + 16384;        // 16384
  float* inv_pf = ws + 32768;        // 32768
  float* flow = ws + 65536;          // 16384*4
  float* pval = ws + 131072;         // 16384*64
  int* pidx = (int*)(ws + 131072 + 1048576);

  k_vm<<<BB, 256, 0, stream>>>(lg, vm, out);
  k_norms<<<(BB * NVV + BB * NPP) / 4, 256, 0, stream>>>(vf, pf, inv_vf, inv_pf);
  // KNN1: queries=vf (raw), keys=pf (norm via inv_pf), 8 chunks of 512 points
  k_knn<<<512, 256, 0, stream>>>(vf, pf, inv_pf, nullptr, pval, pidx, NVV, NPP, 512, 8);
  k_merge_flow<<<256, 64, 0, stream>>>(pval, pidx, vf, pf, pts, vtx, flow, out, 8);
  // KNN2: queries=vf, keys=vf (norm via inv_vf), visible-only, 8 chunks of 256
  k_knn<<<512, 256, 0, stream>>>(vf, vf, inv_vf, vm, pval, pidx, NVV, NVV, 256, 8);
  k_merge_final<<<256, 64, 0, stream>>>(pval, pidx, vf, vm, flow, out, 8);
}

// Round 2
// 659.869 us; speedup vs baseline: 1.0728x; 1.0728x over previous
//
#include <hip/hip_runtime.h>
#include <math.h>

#define BB 8
#define NVV 2048
#define NPP 4096
#define DD 64
#define KK 8

// ws layout (floats):
// vm      : [16384]             @ 0
// inv_vf  : [16384]             @ 16384
// inv_pf  : [32768]             @ 32768
// flow    : [16384][4]          @ 65536
// pval    : [nc*8][16384]       @ 131072           (chunk-major, coalesced)
// pidx    : [nc*8][16384] int   @ 131072 + nc*131072
// nc=32 -> ~34 MB total; fallback nc=8 -> ~8.5 MB

// ============ kernel 1: sigmoid + per-batch min-max normalize ============
__global__ __launch_bounds__(256) void k_vm(const float* __restrict__ logits,
                                            float* __restrict__ vm,
                                            float* __restrict__ out) {
  int b = blockIdx.x, t = threadIdx.x;
  __shared__ float smn[4], smx[4];
  float vals[8];
  float mn = 1e30f, mx = -1e30f;
#pragma unroll
  for (int i = 0; i < 8; i++) {
    float x = logits[b * NVV + t + i * 256];
    float s = 1.0f / (1.0f + expf(-x));
    vals[i] = s;
    mn = fminf(mn, s);
    mx = fmaxf(mx, s);
  }
  for (int o = 32; o; o >>= 1) {
    mn = fminf(mn, __shfl_xor(mn, o, 64));
    mx = fmaxf(mx, __shfl_xor(mx, o, 64));
  }
  int w = t >> 6;
  if ((t & 63) == 0) { smn[w] = mn; smx[w] = mx; }
  __syncthreads();
  mn = fminf(fminf(smn[0], smn[1]), fminf(smn[2], smn[3]));
  mx = fmaxf(fmaxf(smx[0], smx[1]), fmaxf(smx[2], smx[3]));
  float range = mx - mn;
#pragma unroll
  for (int i = 0; i < 8; i++) {
    float v = (vals[i] - mn) / range;
    int g = b * NVV + t + i * 256;
    vm[g] = v;
    out[g * 4 + 3] = v;
  }
}

// ============ kernel 2: per-row inverse norms (one wave per row) ============
__global__ __launch_bounds__(256) void k_norms(const float* __restrict__ vf,
                                               const float* __restrict__ pf,
                                               float* __restrict__ inv_vf,
                                               float* __restrict__ inv_pf) {
  int wave = (blockIdx.x * 256 + threadIdx.x) >> 6;
  int lane = threadIdx.x & 63;
  const float* src;
  float* dst;
  int row;
  if (wave < BB * NVV) { src = vf; dst = inv_vf; row = wave; }
  else { src = pf; dst = inv_pf; row = wave - BB * NVV; }
  float x = src[row * DD + lane];
  float s = x * x;
  for (int o = 32; o; o >>= 1) s += __shfl_xor(s, o, 64);
  if (lane == 0) dst[row] = 1.0f / fmaxf(sqrtf(s), 1e-12f);
}

// ============ kernel 3: partial top-8 cosine KNN ============
// One query per lane; query row pinned in 64 VGPRs (asm barrier prevents
// the compiler re-loading it per key -- R1's VGPR=52 proved it did).
// Keys iterated wave-uniformly (scalar loads). Top-8 kept sorted ascending:
// tv[0] is the running threshold; insert = shift-down chain (~38 VALU).
__global__ __launch_bounds__(256, 4) void k_knn(const float* __restrict__ q,
                                                const float* __restrict__ keys,
                                                const float* __restrict__ inv_key,
                                                const float* __restrict__ mask,
                                                float* __restrict__ pval,
                                                int* __restrict__ pidx,
                                                int nq, int nk, int chunk, int nchunks) {
  int bid = blockIdx.x;
  int ck = bid % nchunks;
  int vb = bid / nchunks;
  int qpb = nq / 256;             // query-blocks per batch
  int batch = vb / qpb;
  int qrow = batch * nq + (vb % qpb) * 256 + threadIdx.x;
  int g = qrow;                   // global query row (batch-major, nq==NVV always)

  float qv[64];
  const float4* qp = (const float4*)(q + (long)qrow * DD);
#pragma unroll
  for (int c = 0; c < 16; c++) {
    float4 t = qp[c];
    qv[4 * c + 0] = t.x; qv[4 * c + 1] = t.y;
    qv[4 * c + 2] = t.z; qv[4 * c + 3] = t.w;
  }
#pragma unroll
  for (int j = 0; j < 64; j++) asm volatile("" : "+v"(qv[j]));  // pin in VGPRs

  float tv[8];
  int ti[8];
#pragma unroll
  for (int k = 0; k < 8; k++) { tv[k] = -3.0e38f; ti[k] = 0; }

  const float* kbase = keys + (long)batch * nk * DD;
  const float* ibase = inv_key + (long)batch * nk;
  const float* mbase = mask ? (mask + (long)batch * nk) : nullptr;
  int p0 = ck * chunk, p1 = p0 + chunk;
  for (int p = p0; p < p1; p++) {
    int pu = __builtin_amdgcn_readfirstlane(p);   // wave-uniform key index
    if (mbase && mbase[pu] < 0.5f) continue;      // uniform scalar branch
    const float4* kp = (const float4*)(kbase + (long)pu * DD);
    float a0 = 0.f, a1 = 0.f, a2 = 0.f, a3 = 0.f;
#pragma unroll
    for (int c = 0; c < 16; c++) {
      float4 kv = kp[c];
      a0 = fmaf(kv.x, qv[4 * c + 0], a0);
      a1 = fmaf(kv.y, qv[4 * c + 1], a1);
      a2 = fmaf(kv.z, qv[4 * c + 2], a2);
      a3 = fmaf(kv.w, qv[4 * c + 3], a3);
    }
    float sim = ((a0 + a1) + (a2 + a3)) * ibase[pu];
    if (sim > tv[0]) {
      bool c1 = sim > tv[1], c2 = sim > tv[2], c3 = sim > tv[3];
      bool c4 = sim > tv[4], c5 = sim > tv[5], c6 = sim > tv[6], c7 = sim > tv[7];
      tv[0] = c1 ? tv[1] : sim;                 ti[0] = c1 ? ti[1] : pu;
      tv[1] = c2 ? tv[2] : (c1 ? sim : tv[1]);  ti[1] = c2 ? ti[2] : (c1 ? pu : ti[1]);
      tv[2] = c3 ? tv[3] : (c2 ? sim : tv[2]);  ti[2] = c3 ? ti[3] : (c2 ? pu : ti[2]);
      tv[3] = c4 ? tv[4] : (c3 ? sim : tv[3]);  ti[3] = c4 ? ti[4] : (c3 ? pu : ti[3]);
      tv[4] = c5 ? tv[5] : (c4 ? sim : tv[4]);  ti[4] = c5 ? ti[5] : (c4 ? pu : ti[4]);
      tv[5] = c6 ? tv[6] : (c5 ? sim : tv[5]);  ti[5] = c6 ? ti[6] : (c5 ? pu : ti[5]);
      tv[6] = c7 ? tv[7] : (c6 ? sim : tv[6]);  ti[6] = c7 ? ti[7] : (c6 ? pu : ti[6]);
      tv[7] = c7 ? sim : tv[7];                 ti[7] = c7 ? pu : ti[7];
    }
  }
  // chunk-major layout: [ck*8+k][16384] -> coalesced stores & merge reads
  float* pv = pval + (long)(ck * 8) * (BB * NVV) + g;
  int* pi = pidx + (long)(ck * 8) * (BB * NVV) + g;
#pragma unroll
  for (int k = 0; k < 8; k++) {
    pv[(long)k * (BB * NVV)] = tv[k];
    pi[(long)k * (BB * NVV)] = ti[k];
  }
}

__device__ __forceinline__ float dot64(const float* __restrict__ a,
                                       const float4* __restrict__ b) {
  float a0 = 0.f, a1 = 0.f, a2 = 0.f, a3 = 0.f;
#pragma unroll
  for (int c = 0; c < 16; c++) {
    float4 y = b[c];
    a0 = fmaf(a[4 * c + 0], y.x, a0);
    a1 = fmaf(a[4 * c + 1], y.y, a1);
    a2 = fmaf(a[4 * c + 2], y.z, a2);
    a3 = fmaf(a[4 * c + 3], y.w, a3);
  }
  return (a0 + a1) + (a2 + a3);
}

__device__ __forceinline__ void merge_topk(const float* __restrict__ pval,
                                           const int* __restrict__ pidx,
                                           int g, int n, float* tv, int* ti) {
#pragma unroll
  for (int k = 0; k < 8; k++) { tv[k] = -3.0e38f; ti[k] = 0; }
  for (int j = 0; j < n; j++) {
    float v = pval[(long)j * (BB * NVV) + g];
    if (v > tv[0]) {
      int id = pidx[(long)j * (BB * NVV) + g];
      bool c1 = v > tv[1], c2 = v > tv[2], c3 = v > tv[3];
      bool c4 = v > tv[4], c5 = v > tv[5], c6 = v > tv[6], c7 = v > tv[7];
      tv[0] = c1 ? tv[1] : v;                 ti[0] = c1 ? ti[1] : id;
      tv[1] = c2 ? tv[2] : (c1 ? v : tv[1]);  ti[1] = c2 ? ti[2] : (c1 ? id : ti[1]);
      tv[2] = c3 ? tv[3] : (c2 ? v : tv[2]);  ti[2] = c3 ? ti[3] : (c2 ? id : ti[2]);
      tv[3] = c4 ? tv[4] : (c3 ? v : tv[3]);  ti[3] = c4 ? ti[4] : (c3 ? id : ti[3]);
      tv[4] = c5 ? tv[5] : (c4 ? v : tv[4]);  ti[4] = c5 ? ti[5] : (c4 ? id : ti[4]);
      tv[5] = c6 ? tv[6] : (c5 ? v : tv[5]);  ti[5] = c6 ? ti[6] : (c5 ? id : ti[5]);
      tv[6] = c7 ? tv[7] : (c6 ? v : tv[6]);  ti[6] = c7 ? ti[7] : (c6 ? id : ti[6]);
      tv[7] = c7 ? v : tv[7];                 ti[7] = c7 ? id : ti[7];
    }
  }
}

// ============ kernel 4: merge KNN1 partials + flow_init ============
// vm cancels in the flow_init ratio -> omitted.
__global__ __launch_bounds__(256) void k_merge_flow(const float* __restrict__ pval,
                                                    const int* __restrict__ pidx,
                                                    const float* __restrict__ vf,
                                                    const float* __restrict__ pf,
                                                    const float* __restrict__ pts,
                                                    const float* __restrict__ vtx,
                                                    float* __restrict__ flow_ws,
                                                    float* __restrict__ out,
                                                    int nchunks) {
  int g = blockIdx.x * 256 + threadIdx.x;  // 0..16383
  int batch = g >> 11;                     // /NVV
  float tv[8];
  int ti[8];
  merge_topk(pval, pidx, g, nchunks * 8, tv, ti);

  float qv[64];
  const float4* qp = (const float4*)(vf + (long)g * DD);
#pragma unroll
  for (int c = 0; c < 16; c++) {
    float4 t = qp[c];
    qv[4 * c + 0] = t.x; qv[4 * c + 1] = t.y;
    qv[4 * c + 2] = t.z; qv[4 * c + 3] = t.w;
  }
  float ax = 0.f, ay = 0.f, az = 0.f, den = 0.f;
  float vx = vtx[g * 3 + 0], vy = vtx[g * 3 + 1], vz = vtx[g * 3 + 2];
#pragma unroll
  for (int k = 0; k < 8; k++) {
    int prow = batch * NPP + ti[k];
    float w = dot64(qv, (const float4*)(pf + (long)prow * DD));
    float ex = pts[prow * 3 + 0] - vx;
    float ey = pts[prow * 3 + 1] - vy;
    float ez = pts[prow * 3 + 2] - vz;
    ax = fmaf(ex, w, ax);
    ay = fmaf(ey, w, ay);
    az = fmaf(ez, w, az);
    den += w;
  }
  float fx = ax / den, fy = ay / den, fz = az / den;
  flow_ws[g * 4 + 0] = fx;
  flow_ws[g * 4 + 1] = fy;
  flow_ws[g * 4 + 2] = fz;
  out[g * 4 + 0] = fx;
  out[g * 4 + 1] = fy;
  out[g * 4 + 2] = fz;
}

// ============ kernel 5: merge KNN2 partials + interpolate invisible ============
__global__ __launch_bounds__(256) void k_merge_final(const float* __restrict__ pval,
                                                     const int* __restrict__ pidx,
                                                     const float* __restrict__ vf,
                                                     const float* __restrict__ vm,
                                                     const float* __restrict__ flow_ws,
                                                     float* __restrict__ out,
                                                     int nchunks) {
  int g = blockIdx.x * 256 + threadIdx.x;
  if (vm[g] >= 0.5f) return;  // visible: out already holds flow_init
  int batch = g >> 11;
  float tv[8];
  int ti[8];
  merge_topk(pval, pidx, g, nchunks * 8, tv, ti);

  float qv[64];
  const float4* qp = (const float4*)(vf + (long)g * DD);
#pragma unroll
  for (int c = 0; c < 16; c++) {
    float4 t = qp[c];
    qv[4 * c + 0] = t.x; qv[4 * c + 1] = t.y;
    qv[4 * c + 2] = t.z; qv[4 * c + 3] = t.w;
  }
  float ax = 0.f, ay = 0.f, az = 0.f, den = 0.f;
#pragma unroll
  for (int k = 0; k < 8; k++) {
    int krow = batch * NVV + ti[k];
    float w = dot64(qv, (const float4*)(vf + (long)krow * DD));
    ax = fmaf(flow_ws[krow * 4 + 0], w, ax);
    ay = fmaf(flow_ws[krow * 4 + 1], w, ay);
    az = fmaf(flow_ws[krow * 4 + 2], w, az);
    den += w;
  }
  out[g * 4 + 0] = ax / den;
  out[g * 4 + 1] = ay / den;
  out[g * 4 + 2] = az / den;
}

extern "C" void kernel_launch(void* const* d_in, const int* in_sizes, int n_in,
                              void* d_out, int out_size, void* d_ws, size_t ws_size,
                              hipStream_t stream) {
  const float* vtx = (const float*)d_in[0];
  const float* pts = (const float*)d_in[1];
  const float* vf = (const float*)d_in[2];
  const float* pf = (const float*)d_in[3];
  const float* lg = (const float*)d_in[4];
  float* out = (float*)d_out;
  float* ws = (float*)d_ws;

  // nc chosen from ws_size (constant across calls -> same work every call)
  int nc = 32;
  size_t need = (size_t)(131072 + 32 * 131072 * 2) * 4;
  if (ws_size < need) nc = 8;

  float* vm = ws;                     // 16384
  float* inv_vf = ws + 16384;         // 16384
  float* inv_pf = ws + 32768;         // 32768
  float* flow = ws + 65536;           // 16384*4
  float* pval = ws + 131072;          // nc*8*16384
  int* pidx = (int*)(ws + 131072 + (size_t)nc * 131072);

  k_vm<<<BB, 256, 0, stream>>>(lg, vm, out);
  k_norms<<<(BB * NVV + BB * NPP) / 4, 256, 0, stream>>>(vf, pf, inv_vf, inv_pf);
  // KNN1: queries=vf (raw), keys=pf (norm via inv_pf), nc chunks of 4096/nc
  k_knn<<<BB * (NVV / 256) * nc, 256, 0, stream>>>(vf, pf, inv_pf, nullptr, pval, pidx,
                                                   NVV, NPP, NPP / nc, nc);
  k_merge_flow<<<BB * NVV / 256, 256, 0, stream>>>(pval, pidx, vf, pf, pts, vtx, flow, out, nc);
  // KNN2: queries=vf, keys=vf (norm via inv_vf), visible-only, nc chunks of 2048/nc
  k_knn<<<BB * (NVV / 256) * nc, 256, 0, stream>>>(vf, vf, inv_vf, vm, pval, pidx,
                                                   NVV, NVV, NVV / nc, nc);
  k_merge_final<<<BB * NVV / 256, 256, 0, stream>>>(pval, pidx, vf, vm, flow, out, nc);
}

// Round 3
// 656.473 us; speedup vs baseline: 1.0783x; 1.0052x over previous
//
#include <hip/hip_runtime.h>
#include <math.h>

#define BB 8
#define NVV 2048
#define NPP 4096
#define DD 64
#define KK 8

// ws layout (floats):
// vm      : [16384]             @ 0
// inv_vf  : [16384]             @ 16384
// inv_pf  : [32768]             @ 32768
// flow    : [16384][4]          @ 65536
// pval    : [nc*8][16384]       @ 131072           (chunk-major, coalesced)
// pidx    : [nc*8][16384] int   @ 131072 + nc*131072
// nc=32 -> ~34 MB total (R2 ran this: ws_size is big enough); fallback nc=8

// ============ kernel 1: vm (blocks 0..7) + row inverse norms (blocks 8..) ============
__global__ __launch_bounds__(256) void k_prep(const float* __restrict__ logits,
                                              const float* __restrict__ vf,
                                              const float* __restrict__ pf,
                                              float* __restrict__ vm,
                                              float* __restrict__ inv_vf,
                                              float* __restrict__ inv_pf,
                                              float* __restrict__ out) {
  if (blockIdx.x < BB) {
    int b = blockIdx.x, t = threadIdx.x;
    __shared__ float smn[4], smx[4];
    float vals[8];
    float mn = 1e30f, mx = -1e30f;
#pragma unroll
    for (int i = 0; i < 8; i++) {
      float x = logits[b * NVV + t + i * 256];
      float s = 1.0f / (1.0f + expf(-x));
      vals[i] = s;
      mn = fminf(mn, s);
      mx = fmaxf(mx, s);
    }
    for (int o = 32; o; o >>= 1) {
      mn = fminf(mn, __shfl_xor(mn, o, 64));
      mx = fmaxf(mx, __shfl_xor(mx, o, 64));
    }
    int w = t >> 6;
    if ((t & 63) == 0) { smn[w] = mn; smx[w] = mx; }
    __syncthreads();
    mn = fminf(fminf(smn[0], smn[1]), fminf(smn[2], smn[3]));
    mx = fmaxf(fmaxf(smx[0], smx[1]), fmaxf(smx[2], smx[3]));
    float range = mx - mn;
#pragma unroll
    for (int i = 0; i < 8; i++) {
      float v = (vals[i] - mn) / range;
      int g = b * NVV + t + i * 256;
      vm[g] = v;
      out[g * 4 + 3] = v;
    }
  } else {
    int wave = ((blockIdx.x - BB) * 256 + threadIdx.x) >> 6;
    int lane = threadIdx.x & 63;
    const float* src;
    float* dst;
    int row;
    if (wave < BB * NVV) { src = vf; dst = inv_vf; row = wave; }
    else { src = pf; dst = inv_pf; row = wave - BB * NVV; }
    float x = src[row * DD + lane];
    float s = x * x;
    for (int o = 32; o; o >>= 1) s += __shfl_xor(s, o, 64);
    if (lane == 0) dst[row] = 1.0f / fmaxf(sqrtf(s), 1e-12f);
  }
}

// ============ kernel 2: partial top-8 cosine KNN ============
// One query per lane; query row pinned in 64 VGPRs. R2 lesson: with
// __launch_bounds__(256,4) the 128-VGPR cap made the allocator put qv in
// AGPRs and v_accvgpr_read it back EVERY key (~64 extra VALU/key,
// VGPR_Count=44). Cap at 2 waves/EU (256 VGPR) so qv stays in arch VGPRs;
// actual usage ~120 still yields 4 waves/SIMD.
__global__ __launch_bounds__(256, 2) void k_knn(const float* __restrict__ q,
                                                const float* __restrict__ keys,
                                                const float* __restrict__ inv_key,
                                                const float* __restrict__ mask,
                                                float* __restrict__ pval,
                                                int* __restrict__ pidx,
                                                int nq, int nk, int chunk, int nchunks) {
  int bid = blockIdx.x;
  int ck = bid % nchunks;
  int vb = bid / nchunks;
  int qpb = nq / 256;             // query-blocks per batch
  int batch = vb / qpb;
  int qrow = batch * nq + (vb % qpb) * 256 + threadIdx.x;
  int g = qrow;

  float qv[64];
  const float4* qp = (const float4*)(q + (long)qrow * DD);
#pragma unroll
  for (int c = 0; c < 16; c++) {
    float4 t = qp[c];
    qv[4 * c + 0] = t.x; qv[4 * c + 1] = t.y;
    qv[4 * c + 2] = t.z; qv[4 * c + 3] = t.w;
  }
#pragma unroll
  for (int j = 0; j < 64; j++) asm volatile("" : "+v"(qv[j]));  // pin in VGPRs

  float tv[8];
  int ti[8];
#pragma unroll
  for (int k = 0; k < 8; k++) { tv[k] = -3.0e38f; ti[k] = 0; }

  const float* kbase = keys + (long)batch * nk * DD;
  const float* ibase = inv_key + (long)batch * nk;
  const float* mbase = mask ? (mask + (long)batch * nk) : nullptr;
  int p0 = ck * chunk, p1 = p0 + chunk;
#pragma unroll 2
  for (int p = p0; p < p1; p++) {
    int pu = __builtin_amdgcn_readfirstlane(p);   // wave-uniform key index
    if (mbase && mbase[pu] < 0.5f) continue;      // uniform scalar branch
    const float4* kp = (const float4*)(kbase + (long)pu * DD);
    float a0 = 0.f, a1 = 0.f, a2 = 0.f, a3 = 0.f;
#pragma unroll
    for (int c = 0; c < 16; c++) {
      float4 kv = kp[c];
      a0 = fmaf(kv.x, qv[4 * c + 0], a0);
      a1 = fmaf(kv.y, qv[4 * c + 1], a1);
      a2 = fmaf(kv.z, qv[4 * c + 2], a2);
      a3 = fmaf(kv.w, qv[4 * c + 3], a3);
    }
    float sim = ((a0 + a1) + (a2 + a3)) * ibase[pu];
    if (sim > tv[0]) {
      bool c1 = sim > tv[1], c2 = sim > tv[2], c3 = sim > tv[3];
      bool c4 = sim > tv[4], c5 = sim > tv[5], c6 = sim > tv[6], c7 = sim > tv[7];
      tv[0] = c1 ? tv[1] : sim;                 ti[0] = c1 ? ti[1] : pu;
      tv[1] = c2 ? tv[2] : (c1 ? sim : tv[1]);  ti[1] = c2 ? ti[2] : (c1 ? pu : ti[1]);
      tv[2] = c3 ? tv[3] : (c2 ? sim : tv[2]);  ti[2] = c3 ? ti[3] : (c2 ? pu : ti[2]);
      tv[3] = c4 ? tv[4] : (c3 ? sim : tv[3]);  ti[3] = c4 ? ti[4] : (c3 ? pu : ti[3]);
      tv[4] = c5 ? tv[5] : (c4 ? sim : tv[4]);  ti[4] = c5 ? ti[5] : (c4 ? pu : ti[4]);
      tv[5] = c6 ? tv[6] : (c5 ? sim : tv[5]);  ti[5] = c6 ? ti[6] : (c5 ? pu : ti[5]);
      tv[6] = c7 ? tv[7] : (c6 ? sim : tv[6]);  ti[6] = c7 ? ti[7] : (c6 ? pu : ti[6]);
      tv[7] = c7 ? sim : tv[7];                 ti[7] = c7 ? pu : ti[7];
    }
  }
  float* pv = pval + (long)(ck * 8) * (BB * NVV) + g;
  int* pi = pidx + (long)(ck * 8) * (BB * NVV) + g;
#pragma unroll
  for (int k = 0; k < 8; k++) {
    pv[(long)k * (BB * NVV)] = tv[k];
    pi[(long)k * (BB * NVV)] = ti[k];
  }
}

__device__ __forceinline__ float dot64(const float* __restrict__ a,
                                       const float4* __restrict__ b) {
  float a0 = 0.f, a1 = 0.f, a2 = 0.f, a3 = 0.f;
#pragma unroll
  for (int c = 0; c < 16; c++) {
    float4 y = b[c];
    a0 = fmaf(a[4 * c + 0], y.x, a0);
    a1 = fmaf(a[4 * c + 1], y.y, a1);
    a2 = fmaf(a[4 * c + 2], y.z, a2);
    a3 = fmaf(a[4 * c + 3], y.w, a3);
  }
  return (a0 + a1) + (a2 + a3);
}

__device__ __forceinline__ void merge_topk(const float* __restrict__ pval,
                                           const int* __restrict__ pidx,
                                           int g, int n, float* tv, int* ti) {
#pragma unroll
  for (int k = 0; k < 8; k++) { tv[k] = -3.0e38f; ti[k] = 0; }
  for (int j = 0; j < n; j++) {
    float v = pval[(long)j * (BB * NVV) + g];
    if (v > tv[0]) {
      int id = pidx[(long)j * (BB * NVV) + g];
      bool c1 = v > tv[1], c2 = v > tv[2], c3 = v > tv[3];
      bool c4 = v > tv[4], c5 = v > tv[5], c6 = v > tv[6], c7 = v > tv[7];
      tv[0] = c1 ? tv[1] : v;                 ti[0] = c1 ? ti[1] : id;
      tv[1] = c2 ? tv[2] : (c1 ? v : tv[1]);  ti[1] = c2 ? ti[2] : (c1 ? id : ti[1]);
      tv[2] = c3 ? tv[3] : (c2 ? v : tv[2]);  ti[2] = c3 ? ti[3] : (c2 ? id : ti[2]);
      tv[3] = c4 ? tv[4] : (c3 ? v : tv[3]);  ti[3] = c4 ? ti[4] : (c3 ? id : ti[3]);
      tv[4] = c5 ? tv[5] : (c4 ? v : tv[4]);  ti[4] = c5 ? ti[5] : (c4 ? id : ti[4]);
      tv[5] = c6 ? tv[6] : (c5 ? v : tv[5]);  ti[5] = c6 ? ti[6] : (c5 ? id : ti[5]);
      tv[6] = c7 ? tv[7] : (c6 ? v : tv[6]);  ti[6] = c7 ? ti[7] : (c6 ? id : ti[6]);
      tv[7] = c7 ? v : tv[7];                 ti[7] = c7 ? id : ti[7];
    }
  }
}

// ============ kernel 3: merge KNN1 partials + flow_init ============
// vm cancels in the flow_init ratio -> omitted.
__global__ __launch_bounds__(256) void k_merge_flow(const float* __restrict__ pval,
                                                    const int* __restrict__ pidx,
                                                    const float* __restrict__ vf,
                                                    const float* __restrict__ pf,
                                                    const float* __restrict__ pts,
                                                    const float* __restrict__ vtx,
                                                    float* __restrict__ flow_ws,
                                                    float* __restrict__ out,
                                                    int nchunks) {
  int g = blockIdx.x * 256 + threadIdx.x;  // 0..16383
  int batch = g >> 11;                     // /NVV
  float tv[8];
  int ti[8];
  merge_topk(pval, pidx, g, nchunks * 8, tv, ti);

  float qv[64];
  const float4* qp = (const float4*)(vf + (long)g * DD);
#pragma unroll
  for (int c = 0; c < 16; c++) {
    float4 t = qp[c];
    qv[4 * c + 0] = t.x; qv[4 * c + 1] = t.y;
    qv[4 * c + 2] = t.z; qv[4 * c + 3] = t.w;
  }
  float ax = 0.f, ay = 0.f, az = 0.f, den = 0.f;
  float vx = vtx[g * 3 + 0], vy = vtx[g * 3 + 1], vz = vtx[g * 3 + 2];
#pragma unroll
  for (int k = 0; k < 8; k++) {
    int prow = batch * NPP + ti[k];
    float w = dot64(qv, (const float4*)(pf + (long)prow * DD));
    float ex = pts[prow * 3 + 0] - vx;
    float ey = pts[prow * 3 + 1] - vy;
    float ez = pts[prow * 3 + 2] - vz;
    ax = fmaf(ex, w, ax);
    ay = fmaf(ey, w, ay);
    az = fmaf(ez, w, az);
    den += w;
  }
  float fx = ax / den, fy = ay / den, fz = az / den;
  flow_ws[g * 4 + 0] = fx;
  flow_ws[g * 4 + 1] = fy;
  flow_ws[g * 4 + 2] = fz;
  out[g * 4 + 0] = fx;
  out[g * 4 + 1] = fy;
  out[g * 4 + 2] = fz;
}

// ============ kernel 4: merge KNN2 partials + interpolate invisible ============
__global__ __launch_bounds__(256) void k_merge_final(const float* __restrict__ pval,
                                                     const int* __restrict__ pidx,
                                                     const float* __restrict__ vf,
                                                     const float* __restrict__ vm,
                                                     const float* __restrict__ flow_ws,
                                                     float* __restrict__ out,
                                                     int nchunks) {
  int g = blockIdx.x * 256 + threadIdx.x;
  if (vm[g] >= 0.5f) return;  // visible: out already holds flow_init
  int batch = g >> 11;
  float tv[8];
  int ti[8];
  merge_topk(pval, pidx, g, nchunks * 8, tv, ti);

  float qv[64];
  const float4* qp = (const float4*)(vf + (long)g * DD);
#pragma unroll
  for (int c = 0; c < 16; c++) {
    float4 t = qp[c];
    qv[4 * c + 0] = t.x; qv[4 * c + 1] = t.y;
    qv[4 * c + 2] = t.z; qv[4 * c + 3] = t.w;
  }
  float ax = 0.f, ay = 0.f, az = 0.f, den = 0.f;
#pragma unroll
  for (int k = 0; k < 8; k++) {
    int krow = batch * NVV + ti[k];
    float w = dot64(qv, (const float4*)(vf + (long)krow * DD));
    ax = fmaf(flow_ws[krow * 4 + 0], w, ax);
    ay = fmaf(flow_ws[krow * 4 + 1], w, ay);
    az = fmaf(flow_ws[krow * 4 + 2], w, az);
    den += w;
  }
  out[g * 4 + 0] = ax / den;
  out[g * 4 + 1] = ay / den;
  out[g * 4 + 2] = az / den;
}

extern "C" void kernel_launch(void* const* d_in, const int* in_sizes, int n_in,
                              void* d_out, int out_size, void* d_ws, size_t ws_size,
                              hipStream_t stream) {
  const float* vtx = (const float*)d_in[0];
  const float* pts = (const float*)d_in[1];
  const float* vf = (const float*)d_in[2];
  const float* pf = (const float*)d_in[3];
  const float* lg = (const float*)d_in[4];
  float* out = (float*)d_out;
  float* ws = (float*)d_ws;

  int nc = 32;
  size_t need = (size_t)(131072 + 32 * 131072 * 2) * 4;
  if (ws_size < need) nc = 8;

  float* vm = ws;                     // 16384
  float* inv_vf = ws + 16384;         // 16384
  float* inv_pf = ws + 32768;         // 32768
  float* flow = ws + 65536;           // 16384*4
  float* pval = ws + 131072;          // nc*8*16384
  int* pidx = (int*)(ws + 131072 + (size_t)nc * 131072);

  k_prep<<<BB + (BB * NVV + BB * NPP) / 4, 256, 0, stream>>>(lg, vf, pf, vm, inv_vf, inv_pf, out);
  // KNN1: queries=vf (raw), keys=pf (norm via inv_pf), nc chunks
  k_knn<<<BB * (NVV / 256) * nc, 256, 0, stream>>>(vf, pf, inv_pf, nullptr, pval, pidx,
                                                   NVV, NPP, NPP / nc, nc);
  k_merge_flow<<<BB * NVV / 256, 256, 0, stream>>>(pval, pidx, vf, pf, pts, vtx, flow, out, nc);
  // KNN2: queries=vf, keys=vf (norm via inv_vf), visible-only
  k_knn<<<BB * (NVV / 256) * nc, 256, 0, stream>>>(vf, vf, inv_vf, vm, pval, pidx,
                                                   NVV, NVV, NVV / nc, nc);
  k_merge_final<<<BB * NVV / 256, 256, 0, stream>>>(pval, pidx, vf, vm, flow, out, nc);
}

// Round 4
// 574.428 us; speedup vs baseline: 1.2323x; 1.1428x over previous
//
#include <hip/hip_runtime.h>
#include <math.h>

#define BB 8
#define NVV 2048
#define NPP 4096
#define DD 64
#define KK 8

// ws layout (floats), nc = chunks per KNN (16 default):
// vm      : [16384]            @ 0
// inv_vf  : [16384]            @ 16384
// inv_pf  : [32768]            @ 32768
// flow    : [16384][4]         @ 65536
// pval1   : [nc*8][16384]      @ 131072
// pidx1   : [nc*8][16384] int  @ 131072 + nc*131072
// pval2   : [nc*8][16384]      @ 131072 + 2*nc*131072
// pidx2   : [nc*8][16384] int  @ 131072 + 3*nc*131072
// nc=16 -> 34.08 MB total (same as R2's nc=32 single-buffer layout, which fit)

// ============ kernel 1: vm (blocks 0..7) + row inverse norms (blocks 8..) ============
__global__ __launch_bounds__(256) void k_prep(const float* __restrict__ logits,
                                              const float* __restrict__ vf,
                                              const float* __restrict__ pf,
                                              float* __restrict__ vm,
                                              float* __restrict__ inv_vf,
                                              float* __restrict__ inv_pf,
                                              float* __restrict__ out) {
  if (blockIdx.x < BB) {
    int b = blockIdx.x, t = threadIdx.x;
    __shared__ float smn[4], smx[4];
    float vals[8];
    float mn = 1e30f, mx = -1e30f;
#pragma unroll
    for (int i = 0; i < 8; i++) {
      float x = logits[b * NVV + t + i * 256];
      float s = 1.0f / (1.0f + expf(-x));
      vals[i] = s;
      mn = fminf(mn, s);
      mx = fmaxf(mx, s);
    }
    for (int o = 32; o; o >>= 1) {
      mn = fminf(mn, __shfl_xor(mn, o, 64));
      mx = fmaxf(mx, __shfl_xor(mx, o, 64));
    }
    int w = t >> 6;
    if ((t & 63) == 0) { smn[w] = mn; smx[w] = mx; }
    __syncthreads();
    mn = fminf(fminf(smn[0], smn[1]), fminf(smn[2], smn[3]));
    mx = fmaxf(fmaxf(smx[0], smx[1]), fmaxf(smx[2], smx[3]));
    float range = mx - mn;
#pragma unroll
    for (int i = 0; i < 8; i++) {
      float v = (vals[i] - mn) / range;
      int g = b * NVV + t + i * 256;
      vm[g] = v;
      out[g * 4 + 3] = v;
    }
  } else {
    int wave = ((blockIdx.x - BB) * 256 + threadIdx.x) >> 6;
    int lane = threadIdx.x & 63;
    const float* src;
    float* dst;
    int row;
    if (wave < BB * NVV) { src = vf; dst = inv_vf; row = wave; }
    else { src = pf; dst = inv_pf; row = wave - BB * NVV; }
    float x = src[row * DD + lane];
    float s = x * x;
    for (int o = 32; o; o >>= 1) s += __shfl_xor(s, o, 64);
    if (lane == 0) dst[row] = 1.0f / fmaxf(sqrtf(s), 1e-12f);
  }
}

// ============ KNN body: partial top-8 cosine, one query per lane ============
// R3 lesson: a one-shot asm pin lets the allocator park qv in AGPRs; the fma
// can't encode SGPR-key + AGPR-query, so it shuttled via v_accvgpr_read
// every key (~64 extra VALU/key, measured 148 inst/key). Re-pinning INSIDE
// the loop makes any non-VGPR home cost 64 copies/iter -> allocator must
// keep qv in arch VGPRs; fma stream becomes v_fmac(vacc, s_key, v_q).
__device__ __forceinline__ void knn_body(const float* __restrict__ q,
                                         const float* __restrict__ keys,
                                         const float* __restrict__ inv_key,
                                         const float* __restrict__ mask,
                                         float* __restrict__ pval,
                                         int* __restrict__ pidx,
                                         int batch, int qblk, int ck,
                                         int nk, int chunk) {
  int qrow = batch * NVV + qblk * 256 + threadIdx.x;

  float qv[64];
  const float4* qp = (const float4*)(q + (long)qrow * DD);
#pragma unroll
  for (int c = 0; c < 16; c++) {
    float4 t = qp[c];
    qv[4 * c + 0] = t.x; qv[4 * c + 1] = t.y;
    qv[4 * c + 2] = t.z; qv[4 * c + 3] = t.w;
  }

  float tv[8];
  int ti[8];
#pragma unroll
  for (int k = 0; k < 8; k++) { tv[k] = -3.0e38f; ti[k] = 0; }

  const float* kbase = keys + (long)batch * nk * DD;
  const float* ibase = inv_key + (long)batch * nk;
  const float* mbase = mask ? (mask + (long)batch * nk) : nullptr;
  int p0 = ck * chunk, p1 = p0 + chunk;
#pragma unroll 2
  for (int p = p0; p < p1; p++) {
    // per-iteration pin: qv must live in arch VGPRs here, every key
#pragma unroll
    for (int j = 0; j < 64; j++) asm volatile("" : "+v"(qv[j]));
    int pu = __builtin_amdgcn_readfirstlane(p);   // wave-uniform key index
    if (mbase && mbase[pu] < 0.5f) continue;      // uniform scalar branch
    const float4* kp = (const float4*)(kbase + (long)pu * DD);
    float a0 = 0.f, a1 = 0.f, a2 = 0.f, a3 = 0.f;
#pragma unroll
    for (int c = 0; c < 16; c++) {
      float4 kv = kp[c];
      a0 = fmaf(kv.x, qv[4 * c + 0], a0);
      a1 = fmaf(kv.y, qv[4 * c + 1], a1);
      a2 = fmaf(kv.z, qv[4 * c + 2], a2);
      a3 = fmaf(kv.w, qv[4 * c + 3], a3);
    }
    float sim = ((a0 + a1) + (a2 + a3)) * ibase[pu];
    if (sim > tv[0]) {
      bool c1 = sim > tv[1], c2 = sim > tv[2], c3 = sim > tv[3];
      bool c4 = sim > tv[4], c5 = sim > tv[5], c6 = sim > tv[6], c7 = sim > tv[7];
      tv[0] = c1 ? tv[1] : sim;                 ti[0] = c1 ? ti[1] : pu;
      tv[1] = c2 ? tv[2] : (c1 ? sim : tv[1]);  ti[1] = c2 ? ti[2] : (c1 ? pu : ti[1]);
      tv[2] = c3 ? tv[3] : (c2 ? sim : tv[2]);  ti[2] = c3 ? ti[3] : (c2 ? pu : ti[2]);
      tv[3] = c4 ? tv[4] : (c3 ? sim : tv[3]);  ti[3] = c4 ? ti[4] : (c3 ? pu : ti[3]);
      tv[4] = c5 ? tv[5] : (c4 ? sim : tv[4]);  ti[4] = c5 ? ti[5] : (c4 ? pu : ti[4]);
      tv[5] = c6 ? tv[6] : (c5 ? sim : tv[5]);  ti[5] = c6 ? ti[6] : (c5 ? pu : ti[5]);
      tv[6] = c7 ? tv[7] : (c6 ? sim : tv[6]);  ti[6] = c7 ? ti[7] : (c6 ? pu : ti[6]);
      tv[7] = c7 ? sim : tv[7];                 ti[7] = c7 ? pu : ti[7];
    }
  }
  float* pv = pval + (long)(ck * 8) * (BB * NVV) + qrow;
  int* pi = pidx + (long)(ck * 8) * (BB * NVV) + qrow;
#pragma unroll
  for (int k = 0; k < 8; k++) {
    pv[(long)k * (BB * NVV)] = tv[k];
    pi[(long)k * (BB * NVV)] = ti[k];
  }
}

// ============ kernel 2: fused KNN1 + KNN2 (independent workloads) ============
__global__ __launch_bounds__(256, 2) void k_knn2x(const float* __restrict__ vf,
                                                  const float* __restrict__ pf,
                                                  const float* __restrict__ inv_vf,
                                                  const float* __restrict__ inv_pf,
                                                  const float* __restrict__ vm,
                                                  float* __restrict__ pval1,
                                                  int* __restrict__ pidx1,
                                                  float* __restrict__ pval2,
                                                  int* __restrict__ pidx2,
                                                  int nc) {
  int nb1 = BB * (NVV / 256) * nc;
  int bid = blockIdx.x;
  if (bid < nb1) {
    int ck = bid % nc;
    int vb = bid / nc;
    knn_body(vf, pf, inv_pf, nullptr, pval1, pidx1,
             vb / (NVV / 256), vb % (NVV / 256), ck, NPP, NPP / nc);
  } else {
    bid -= nb1;
    int ck = bid % nc;
    int vb = bid / nc;
    knn_body(vf, vf, inv_vf, vm, pval2, pidx2,
             vb / (NVV / 256), vb % (NVV / 256), ck, NVV, NVV / nc);
  }
}

__device__ __forceinline__ float dot64(const float* __restrict__ a,
                                       const float4* __restrict__ b) {
  float a0 = 0.f, a1 = 0.f, a2 = 0.f, a3 = 0.f;
#pragma unroll
  for (int c = 0; c < 16; c++) {
    float4 y = b[c];
    a0 = fmaf(a[4 * c + 0], y.x, a0);
    a1 = fmaf(a[4 * c + 1], y.y, a1);
    a2 = fmaf(a[4 * c + 2], y.z, a2);
    a3 = fmaf(a[4 * c + 3], y.w, a3);
  }
  return (a0 + a1) + (a2 + a3);
}

__device__ __forceinline__ void merge_topk(const float* __restrict__ pval,
                                           const int* __restrict__ pidx,
                                           int g, int n, float* tv, int* ti) {
#pragma unroll
  for (int k = 0; k < 8; k++) { tv[k] = -3.0e38f; ti[k] = 0; }
  for (int j = 0; j < n; j++) {
    float v = pval[(long)j * (BB * NVV) + g];
    if (v > tv[0]) {
      int id = pidx[(long)j * (BB * NVV) + g];
      bool c1 = v > tv[1], c2 = v > tv[2], c3 = v > tv[3];
      bool c4 = v > tv[4], c5 = v > tv[5], c6 = v > tv[6], c7 = v > tv[7];
      tv[0] = c1 ? tv[1] : v;                 ti[0] = c1 ? ti[1] : id;
      tv[1] = c2 ? tv[2] : (c1 ? v : tv[1]);  ti[1] = c2 ? ti[2] : (c1 ? id : ti[1]);
      tv[2] = c3 ? tv[3] : (c2 ? v : tv[2]);  ti[2] = c3 ? ti[3] : (c2 ? id : ti[2]);
      tv[3] = c4 ? tv[4] : (c3 ? v : tv[3]);  ti[3] = c4 ? ti[4] : (c3 ? id : ti[3]);
      tv[4] = c5 ? tv[5] : (c4 ? v : tv[4]);  ti[4] = c5 ? ti[5] : (c4 ? id : ti[4]);
      tv[5] = c6 ? tv[6] : (c5 ? v : tv[5]);  ti[5] = c6 ? ti[6] : (c5 ? id : ti[5]);
      tv[6] = c7 ? tv[7] : (c6 ? v : tv[6]);  ti[6] = c7 ? ti[7] : (c6 ? id : ti[6]);
      tv[7] = c7 ? v : tv[7];                 ti[7] = c7 ? id : ti[7];
    }
  }
}

// ============ kernel 3: merge KNN1 partials + flow_init ============
// vm cancels in the flow_init ratio -> omitted.
__global__ __launch_bounds__(256) void k_merge_flow(const float* __restrict__ pval,
                                                    const int* __restrict__ pidx,
                                                    const float* __restrict__ vf,
                                                    const float* __restrict__ pf,
                                                    const float* __restrict__ pts,
                                                    const float* __restrict__ vtx,
                                                    float* __restrict__ flow_ws,
                                                    float* __restrict__ out,
                                                    int nchunks) {
  int g = blockIdx.x * 256 + threadIdx.x;  // 0..16383
  int batch = g >> 11;                     // /NVV
  float tv[8];
  int ti[8];
  merge_topk(pval, pidx, g, nchunks * 8, tv, ti);

  float qv[64];
  const float4* qp = (const float4*)(vf + (long)g * DD);
#pragma unroll
  for (int c = 0; c < 16; c++) {
    float4 t = qp[c];
    qv[4 * c + 0] = t.x; qv[4 * c + 1] = t.y;
    qv[4 * c + 2] = t.z; qv[4 * c + 3] = t.w;
  }
  float ax = 0.f, ay = 0.f, az = 0.f, den = 0.f;
  float vx = vtx[g * 3 + 0], vy = vtx[g * 3 + 1], vz = vtx[g * 3 + 2];
#pragma unroll
  for (int k = 0; k < 8; k++) {
    int prow = batch * NPP + ti[k];
    float w = dot64(qv, (const float4*)(pf + (long)prow * DD));
    float ex = pts[prow * 3 + 0] - vx;
    float ey = pts[prow * 3 + 1] - vy;
    float ez = pts[prow * 3 + 2] - vz;
    ax = fmaf(ex, w, ax);
    ay = fmaf(ey, w, ay);
    az = fmaf(ez, w, az);
    den += w;
  }
  float fx = ax / den, fy = ay / den, fz = az / den;
  flow_ws[g * 4 + 0] = fx;
  flow_ws[g * 4 + 1] = fy;
  flow_ws[g * 4 + 2] = fz;
  out[g * 4 + 0] = fx;
  out[g * 4 + 1] = fy;
  out[g * 4 + 2] = fz;
}

// ============ kernel 4: merge KNN2 partials + interpolate invisible ============
__global__ __launch_bounds__(256) void k_merge_final(const float* __restrict__ pval,
                                                     const int* __restrict__ pidx,
                                                     const float* __restrict__ vf,
                                                     const float* __restrict__ vm,
                                                     const float* __restrict__ flow_ws,
                                                     float* __restrict__ out,
                                                     int nchunks) {
  int g = blockIdx.x * 256 + threadIdx.x;
  if (vm[g] >= 0.5f) return;  // visible: out already holds flow_init
  int batch = g >> 11;
  float tv[8];
  int ti[8];
  merge_topk(pval, pidx, g, nchunks * 8, tv, ti);

  float qv[64];
  const float4* qp = (const float4*)(vf + (long)g * DD);
#pragma unroll
  for (int c = 0; c < 16; c++) {
    float4 t = qp[c];
    qv[4 * c + 0] = t.x; qv[4 * c + 1] = t.y;
    qv[4 * c + 2] = t.z; qv[4 * c + 3] = t.w;
  }
  float ax = 0.f, ay = 0.f, az = 0.f, den = 0.f;
#pragma unroll
  for (int k = 0; k < 8; k++) {
    int krow = batch * NVV + ti[k];
    float w = dot64(qv, (const float4*)(vf + (long)krow * DD));
    ax = fmaf(flow_ws[krow * 4 + 0], w, ax);
    ay = fmaf(flow_ws[krow * 4 + 1], w, ay);
    az = fmaf(flow_ws[krow * 4 + 2], w, az);
    den += w;
  }
  out[g * 4 + 0] = ax / den;
  out[g * 4 + 1] = ay / den;
  out[g * 4 + 2] = az / den;
}

extern "C" void kernel_launch(void* const* d_in, const int* in_sizes, int n_in,
                              void* d_out, int out_size, void* d_ws, size_t ws_size,
                              hipStream_t stream) {
  const float* vtx = (const float*)d_in[0];
  const float* pts = (const float*)d_in[1];
  const float* vf = (const float*)d_in[2];
  const float* pf = (const float*)d_in[3];
  const float* lg = (const float*)d_in[4];
  float* out = (float*)d_out;
  float* ws = (float*)d_ws;

  // nc per KNN; nc=16 x 2 KNNs = 34.08 MB, same total as R2 (which fit)
  int nc = 16;
  size_t need = ((size_t)131072 + (size_t)4 * nc * 131072) * 4;
  if (ws_size < need) nc = 8;

  float* vm = ws;                     // 16384
  float* inv_vf = ws + 16384;         // 16384
  float* inv_pf = ws + 32768;         // 32768
  float* flow = ws + 65536;           // 16384*4
  float* pval1 = ws + 131072;
  int* pidx1 = (int*)(pval1 + (size_t)nc * 131072);
  float* pval2 = (float*)(pidx1 + (size_t)nc * 131072);
  int* pidx2 = (int*)(pval2 + (size_t)nc * 131072);

  k_prep<<<BB + (BB * NVV + BB * NPP) / 4, 256, 0, stream>>>(lg, vf, pf, vm, inv_vf, inv_pf, out);
  k_knn2x<<<2 * BB * (NVV / 256) * nc, 256, 0, stream>>>(vf, pf, inv_vf, inv_pf, vm,
                                                         pval1, pidx1, pval2, pidx2, nc);
  k_merge_flow<<<BB * NVV / 256, 256, 0, stream>>>(pval1, pidx1, vf, pf, pts, vtx, flow, out, nc);
  k_merge_final<<<BB * NVV / 256, 256, 0, stream>>>(pval2, pidx2, vf, vm, flow, out, nc);
}